// Round 3
// baseline (298.871 us; speedup 1.0000x reference)
//
#include <hip/hip_runtime.h>
#include <hip/hip_bf16.h>

// LocallyConnected2d: x(32,48,64,64) f32, weight(48,64,64,48,3,3) f32, bias(48) f32
// out(32,48,64,64) f32.  Per-location GEMM M=32(b) x N=48(o) x K=432, bf16 MFMA.
//
// R3 structure: each wave issues its ENTIRE weight stream (28 x float4/lane,
// 28 KB/wave in flight) before the barrier; x staging overlaps in the same
// queue; f32->bf16 conversion during the drain; MFMA loop is stall-free.

#define NB 32      // batch
#define NC 48      // in channels
#define NO 48      // out channels
#define NH 64
#define NW 64
#define NL 4096    // 64*64 locations
#define NK 432     // 48*9
#define PITCH 456  // LDS row pitch in bf16 (912 B; b128 lane-stride = 4 banks -> conflict-free)
#define NTHREADS 192

typedef __bf16 bf16x8 __attribute__((ext_vector_type(8)));
typedef float f32x4 __attribute__((ext_vector_type(4)));

__global__ __launch_bounds__(NTHREADS, 3)
void lc2d_kernel(const float* __restrict__ x, const float* __restrict__ wgt,
                 const float* __restrict__ bias, float* __restrict__ out) {
    __shared__ __bf16 xs[NB * PITCH];   // 29184 B

    const int t = threadIdx.x;
    const int bid = blockIdx.x;
    // chunked XCD swizzle: each XCD gets 512 consecutive locations (8 h-rows)
    const int l = (bid & 7) * 512 + (bid >> 3);
    const int h = l >> 6;
    const int w = l & 63;

    const int lane = t & 63, wid = t >> 6;      // wid = o-third (0..2)
    const int rrow = lane & 15, g = lane >> 4;
    const int o = wid * 16 + rrow;

    // ---- 1) issue ALL weight loads up-front: 28 x float4 per lane, one queue
    const float* wp = wgt + ((size_t)o * NL + l) * NK + g * 8;
    float4 wf[28];
#pragma unroll
    for (int ks = 0; ks < 13; ++ks) {
        wf[2 * ks]     = *(const float4*)(wp + ks * 32);
        wf[2 * ks + 1] = *(const float4*)(wp + ks * 32 + 4);
    }
    {   // ks = 13: k = 416 + g*8; lanes g>=2 map to k>=432 (pad) -> zero (also avoids OOB)
        const float4 z4 = {0.f, 0.f, 0.f, 0.f};
        wf[26] = z4; wf[27] = z4;
        if (g < 2) {
            wf[26] = *(const float4*)(wp + 13 * 32);
            wf[27] = *(const float4*)(wp + 13 * 32 + 4);
        }
    }
    const float bsv = bias[o];   // issued early, consumed in epilogue

    // ---- zero the K-pad region [432, 456) of all 32 rows: 32 rows x 3 bf16x8
    if (t < 96) {
        const int row = t & 31, chunk = t >> 5;
        bf16x8 z = {};
        *(bf16x8*)&xs[row * PITCH + NK + chunk * 8] = z;
    }

    // ---- 2) stage x patches: task (b,c) copies its 3x3 window (k = c*9+di*3+dj)
    // 1536 tasks / 192 threads = 8 iterations; loads queue behind weight stream.
#pragma unroll 4
    for (int it = 0; it < 8; ++it) {
        const int idx = t + it * NTHREADS;
        const int b = idx / NC, c = idx - b * NC;
        const float* xb = x + ((size_t)(b * NC + c)) * (NH * NW);
        float v[9];
#pragma unroll
        for (int di = 0; di < 3; ++di) {
            const int y = h + di - 1;
            const bool yok = (unsigned)y < (unsigned)NH;
#pragma unroll
            for (int dj = 0; dj < 3; ++dj) {
                const int xc = w + dj - 1;
                v[di * 3 + dj] = (yok && (unsigned)xc < (unsigned)NW) ? xb[y * NW + xc] : 0.0f;
            }
        }
        __bf16* dst = &xs[b * PITCH + c * 9];
#pragma unroll
        for (int k9 = 0; k9 < 9; ++k9) dst[k9] = (__bf16)v[k9];
    }

    // ---- 3) convert weights f32->bf16 in arrival order (during the drain)
    bf16x8 wb[14];
#pragma unroll
    for (int ks = 0; ks < 14; ++ks) {
        const float4 f0 = wf[2 * ks], f1 = wf[2 * ks + 1];
        bf16x8 bv;
        bv[0] = (__bf16)f0.x; bv[1] = (__bf16)f0.y; bv[2] = (__bf16)f0.z; bv[3] = (__bf16)f0.w;
        bv[4] = (__bf16)f1.x; bv[5] = (__bf16)f1.y; bv[6] = (__bf16)f1.z; bv[7] = (__bf16)f1.w;
        wb[ks] = bv;
    }

    __syncthreads();

    // ---- 4) stall-free MFMA loop: operands all in regs / LDS
    const __bf16* pa0 = &xs[rrow * PITCH + g * 8];          // b 0..15
    const __bf16* pa1 = &xs[(16 + rrow) * PITCH + g * 8];   // b 16..31

    f32x4 acc0 = {0.f, 0.f, 0.f, 0.f};
    f32x4 acc1 = {0.f, 0.f, 0.f, 0.f};
#pragma unroll
    for (int ks = 0; ks < 14; ++ks) {
        bf16x8 av0 = *(const bf16x8*)(pa0 + ks * 32);
        bf16x8 av1 = *(const bf16x8*)(pa1 + ks * 32);
        acc0 = __builtin_amdgcn_mfma_f32_16x16x32_bf16(av0, wb[ks], acc0, 0, 0, 0);
        acc1 = __builtin_amdgcn_mfma_f32_16x16x32_bf16(av1, wb[ks], acc1, 0, 0, 0);
    }

    // ---- epilogue: C layout col(lane&15)=o, row((lane>>4)*4+r)=b
#pragma unroll
    for (int r = 0; r < 4; ++r) {
        const int b0 = g * 4 + r;
        out[((size_t)(b0 * NO + o)) * NL + l] = acc0[r] + bsv;
        out[((size_t)((16 + b0) * NO + o)) * NL + l] = acc1[r] + bsv;
    }
}

extern "C" void kernel_launch(void* const* d_in, const int* in_sizes, int n_in,
                              void* d_out, int out_size, void* d_ws, size_t ws_size,
                              hipStream_t stream) {
    const float* x    = (const float*)d_in[0];
    const float* wgt  = (const float*)d_in[1];
    const float* bias = (const float*)d_in[2];
    float* out = (float*)d_out;
    lc2d_kernel<<<dim3(NL), dim3(NTHREADS), 0, stream>>>(x, wgt, bias, out);
}

// Round 4
// 288.044 us; speedup vs baseline: 1.0376x; 1.0376x over previous
//
#include <hip/hip_runtime.h>
#include <hip/hip_bf16.h>

// LocallyConnected2d: x(32,48,64,64) f32, weight(48,64,64,48,3,3) f32, bias(48) f32
// out(32,48,64,64) f32.  Per-location GEMM M=32(b) x N=48(o) x K=432, bf16 MFMA.
//
// R4: (1) weight staging is LANE-CONTIGUOUS (coalesced float4 row-copy into
// LDS bf16, batched 7-deep per wave) -- kills the 16-lines-per-instruction
// scatter of R2/R3; (2) outputs go to a transposed scratch out_t[l][b*48+o]
// (per-block contiguous 6 KB) + a tiled transpose kernel -> coalesced final
// stores, killing the 11x write amplification.

#define NB 32
#define NC 48
#define NO 48
#define NH 64
#define NW 64
#define NL 4096
#define NK 432
#define PITCH 456   // bf16 units; 912 B row stride (16B-aligned)
#define NM 1536     // NB*NO
#define NTHREADS 384

typedef __bf16 bf16x8 __attribute__((ext_vector_type(8)));
typedef __bf16 bf16x4 __attribute__((ext_vector_type(4)));
typedef float f32x4 __attribute__((ext_vector_type(4)));

template <int MODE>   // 0 = direct scattered stores, 1 = via transposed scratch
__global__ __launch_bounds__(NTHREADS, 3)
void lc2d_kernel(const float* __restrict__ x, const float* __restrict__ wgt,
                 const float* __restrict__ bias, float* __restrict__ outp) {
    __shared__ __bf16 xs[NB * PITCH];   // 29184 B
    __shared__ __bf16 ws[NO * PITCH];   // 43776 B   (total 72960 -> 2 blocks/CU)

    const int t = threadIdx.x;
    const int bid = blockIdx.x;
    const int l = (bid & 7) * 512 + (bid >> 3);   // chunked XCD swizzle
    const int h = l >> 6;
    const int w = l & 63;

    const float* wbase = wgt + (size_t)l * NK;    // + o*NL*NK + granule*4

    // ---- weight staging: 48 rows x 108 float4-granules, lane-contiguous.
    // granule gi -> row = gi/108, col = gi%108; addr contiguous in col.
    // Batch A: gi = t + {0..6}*384 ; Batch B: gi = t + {7..12}*384 ; tail it=13 (t<192).
    float4 va[7], vb[6];
#pragma unroll
    for (int i = 0; i < 7; ++i) {
        const int gi = t + i * NTHREADS;
        const int row = gi / 108, c = gi - row * 108;
        va[i] = *(const float4*)(wbase + (size_t)row * (NL * NK) + c * 4);
    }
#pragma unroll
    for (int i = 0; i < 6; ++i) {
        const int gi = t + (7 + i) * NTHREADS;
        const int row = gi / 108, c = gi - row * 108;
        vb[i] = *(const float4*)(wbase + (size_t)row * (NL * NK) + c * 4);
    }
    float4 vt;
    if (t < 5184 - 13 * NTHREADS) {   // tail: 192 granules
        const int gi = t + 13 * NTHREADS;
        const int row = gi / 108, c = gi - row * 108;
        vt = *(const float4*)(wbase + (size_t)row * (NL * NK) + c * 4);
    }

    // ---- x staging: all 36 loads hoisted, then all LDS writes
    float xv[4][9];
#pragma unroll
    for (int it = 0; it < 4; ++it) {
        const int idx = t + it * NTHREADS;
        const int b = idx / NC, c = idx - b * NC;
        const float* xb = x + ((size_t)(b * NC + c)) * (NH * NW);
#pragma unroll
        for (int di = 0; di < 3; ++di) {
            const int y = h + di - 1;
            const bool yok = (unsigned)y < (unsigned)NH;
#pragma unroll
            for (int dj = 0; dj < 3; ++dj) {
                const int xc = w + dj - 1;
                xv[it][di * 3 + dj] =
                    (yok && (unsigned)xc < (unsigned)NW) ? xb[y * NW + xc] : 0.0f;
            }
        }
    }

    // ---- zero K-pad [432,456) of both tiles: ws 48 rows, xs 32 rows (3 x bf16x8 each)
    {
        bf16x8 z = {};
        if (t < 144) { const int r = t / 3, ch = t - r * 3; *(bf16x8*)&ws[r * PITCH + NK + ch * 8] = z; }
        else if (t < 240) { const int q = t - 144; const int r = q / 3, ch = q - r * 3; *(bf16x8*)&xs[r * PITCH + NK + ch * 8] = z; }
    }

    // ---- drain & convert: weights f32 -> bf16 LDS
#pragma unroll
    for (int i = 0; i < 7; ++i) {
        const int gi = t + i * NTHREADS;
        const int row = gi / 108, c = gi - row * 108;
        bf16x4 bv4; bv4[0] = (__bf16)va[i].x; bv4[1] = (__bf16)va[i].y;
        bv4[2] = (__bf16)va[i].z; bv4[3] = (__bf16)va[i].w;
        *(bf16x4*)&ws[row * PITCH + c * 4] = bv4;
    }
#pragma unroll
    for (int i = 0; i < 6; ++i) {
        const int gi = t + (7 + i) * NTHREADS;
        const int row = gi / 108, c = gi - row * 108;
        bf16x4 bv4; bv4[0] = (__bf16)vb[i].x; bv4[1] = (__bf16)vb[i].y;
        bv4[2] = (__bf16)vb[i].z; bv4[3] = (__bf16)vb[i].w;
        *(bf16x4*)&ws[row * PITCH + c * 4] = bv4;
    }
    if (t < 5184 - 13 * NTHREADS) {
        const int gi = t + 13 * NTHREADS;
        const int row = gi / 108, c = gi - row * 108;
        bf16x4 bv4; bv4[0] = (__bf16)vt.x; bv4[1] = (__bf16)vt.y;
        bv4[2] = (__bf16)vt.z; bv4[3] = (__bf16)vt.w;
        *(bf16x4*)&ws[row * PITCH + c * 4] = bv4;
    }

    // ---- x -> LDS bf16
#pragma unroll
    for (int it = 0; it < 4; ++it) {
        const int idx = t + it * NTHREADS;
        const int b = idx / NC, c = idx - b * NC;
        __bf16* dst = &xs[b * PITCH + c * 9];
#pragma unroll
        for (int k9 = 0; k9 < 9; ++k9) dst[k9] = (__bf16)xv[it][k9];
    }

    __syncthreads();

    // ---- compute: 6 waves = (b-half mt) x (o-third ot); 14 MFMA each
    const int lane = t & 63, wid = t >> 6;
    const int mt = wid & 1, ot = wid >> 1;
    const int rrow = lane & 15, g = lane >> 4;
    const int o = ot * 16 + rrow;

    const __bf16* pa = &xs[(mt * 16 + rrow) * PITCH + g * 8];
    const __bf16* pb = &ws[o * PITCH + g * 8];

    f32x4 acc = {0.f, 0.f, 0.f, 0.f};
#pragma unroll
    for (int ks = 0; ks < 14; ++ks) {
        bf16x8 av = *(const bf16x8*)(pa + ks * 32);
        bf16x8 bv = *(const bf16x8*)(pb + ks * 32);
        acc = __builtin_amdgcn_mfma_f32_16x16x32_bf16(av, bv, acc, 0, 0, 0);
    }

    // ---- epilogue: C layout col(lane&15)=o, row((lane>>4)*4+r)=b
    const float bsv = bias[o];
#pragma unroll
    for (int r = 0; r < 4; ++r) {
        const int b = mt * 16 + g * 4 + r;
        if (MODE == 1) {
            // out_t[l][b*48+o]: per-block contiguous 6 KB -> zero write amplification
            outp[(size_t)l * NM + b * NO + o] = acc[r] + bsv;
        } else {
            outp[((size_t)(b * NO + o)) * NL + l] = acc[r] + bsv;
        }
    }
}

// out[m][l] = out_t[l][m], m = b*48+o.  32x32 tiles, fully coalesced both sides.
__global__ __launch_bounds__(256)
void lc2d_transpose(const float* __restrict__ src, float* __restrict__ dst) {
    __shared__ float tile[32][33];
    const int bid = blockIdx.x;
    const int mt = bid % (NM / 32), lt = bid / (NM / 32);
    const int m0 = mt * 32, l0 = lt * 32;
    const int tid = threadIdx.x;
    const int c = tid & 31, rq = tid >> 5;   // 8 rows per pass
#pragma unroll
    for (int p = 0; p < 4; ++p) {
        const int lr = p * 8 + rq;
        tile[lr][c] = src[(size_t)(l0 + lr) * NM + m0 + c];
    }
    __syncthreads();
#pragma unroll
    for (int p = 0; p < 4; ++p) {
        const int mr = p * 8 + rq;
        dst[(size_t)(m0 + mr) * NL + l0 + c] = tile[c][mr];
    }
}

extern "C" void kernel_launch(void* const* d_in, const int* in_sizes, int n_in,
                              void* d_out, int out_size, void* d_ws, size_t ws_size,
                              hipStream_t stream) {
    const float* x    = (const float*)d_in[0];
    const float* wgt  = (const float*)d_in[1];
    const float* bias = (const float*)d_in[2];
    float* out = (float*)d_out;

    const size_t scratch_need = (size_t)NL * NM * sizeof(float);   // 25.2 MB
    if (ws_size >= scratch_need) {
        float* out_t = (float*)d_ws;
        lc2d_kernel<1><<<dim3(NL), dim3(NTHREADS), 0, stream>>>(x, wgt, bias, out_t);
        lc2d_transpose<<<dim3((NM / 32) * (NL / 32)), dim3(256), 0, stream>>>(out_t, out);
    } else {
        lc2d_kernel<0><<<dim3(NL), dim3(NTHREADS), 0, stream>>>(x, wgt, bias, out);
    }
}

// Round 5
// 183.518 us; speedup vs baseline: 1.6286x; 1.5696x over previous
//
#include <hip/hip_runtime.h>
#include <hip/hip_bf16.h>

// LocallyConnected2d: x(32,48,64,64) f32, weight(48,64,64,48,3,3) f32, bias(48) f32
// out(32,48,64,64) f32.  Per-location GEMM M=32(b) x N=48(o) x K=432, bf16 MFMA.
//
// R5: two-pass im2col. K1 materializes unf[l][b][kp448] bf16 with both sides
// coalesced (kills the 57M-request x scatter of R1-R4). K2 (main) reads its
// A-patch dense from unf, weights via coalesced row-copy -> LDS (43.7 KB only),
// stores to transposed scratch. K3 transposes to final layout.

#define NB 32
#define NC 48
#define NO 48
#define NH 64
#define NW 64
#define NL 4096
#define NK 432
#define KPAD 448     // padded K (14*32)
#define PITCH 456    // ws LDS row pitch (bf16)
#define NM 1536      // NB*NO
#define UROW 14336   // NB*KPAD  (elems per l in unf)

typedef __bf16 bf16x8 __attribute__((ext_vector_type(8)));
typedef __bf16 bf16x4 __attribute__((ext_vector_type(4)));
typedef float f32x4 __attribute__((ext_vector_type(4)));

// ---------------- K1: unfold  x -> unf[l][b][kp]  (bf16) ----------------
// block = (h, b): stage x[b][:][h-1..h+1][:] rows in LDS (coalesced 256-B rows),
// then emit 64 w-positions x 448 kp as contiguous bf16x8 stores.
__global__ __launch_bounds__(256)
void lc2d_unfold(const float* __restrict__ x, __bf16* __restrict__ unf) {
    __shared__ float xl[NC * 3 * 66];   // 38016 B, row-padded [c*3+yy][66], col 0/65 = halo
    const int bid = blockIdx.x;
    const int h = bid >> 5;             // 0..63
    const int b = bid & 31;             // 0..31
    const int t = threadIdx.x;

    // load 48c x 3yy x 64w, each 64-lane group = one contiguous 256-B row
#pragma unroll
    for (int it = 0; it < 36; ++it) {
        const int idx = t + it * 256;
        const int row = idx >> 6;       // c*3+yy, 0..143
        const int w = idx & 63;
        const int c = row / 3, yy = row - c * 3;
        const int y = h + yy - 1;
        float v = 0.0f;
        if ((unsigned)y < (unsigned)NH)
            v = x[(((size_t)(b * NC + c)) * NH + y) * NW + w];
        xl[row * 66 + 1 + w] = v;
    }
    if (t < 144) { xl[t * 66] = 0.0f; xl[t * 66 + 65] = 0.0f; }
    __syncthreads();

    // emit: 64 w x 56 bf16x8-chunks; lanes consecutive -> contiguous 896-B runs
    __bf16* dst = unf + ((size_t)h * 64 * NB + b) * KPAD;
#pragma unroll
    for (int it = 0; it < 14; ++it) {
        const int idx = t + it * 256;   // 0..3583
        const int w = idx / 56, kc = idx - w * 56;
        bf16x8 val = {};
        if (kc < 54) {                  // kc 54,55 are K-pad -> zeros
#pragma unroll
            for (int j = 0; j < 8; ++j) {
                const int kp = kc * 8 + j;
                const int c = kp / 9, r9 = kp - c * 9;
                const int di = r9 / 3, dj = r9 - di * 3;
                val[j] = (__bf16)xl[(c * 3 + di) * 66 + w + dj];
            }
        }
        *(bf16x8*)(dst + (size_t)w * UROW + kc * 8) = val;
    }
}

// ---------------- K2: main  per-l GEMM, A from unf (dense), B via LDS ----------------
__global__ __launch_bounds__(384, 2)
void lc2d_main(const __bf16* __restrict__ unf, const float* __restrict__ wgt,
               const float* __restrict__ bias, float* __restrict__ out_t) {
    __shared__ __bf16 ws[NO * PITCH];   // 43776 B -> 3 blocks/CU by LDS

    const int t = threadIdx.x;
    const int bid = blockIdx.x;
    const int l = (bid & 7) * 512 + (bid >> 3);   // chunked XCD swizzle

    const int lane = t & 63, wid = t >> 6;
    const int mt = wid & 1, ot = wid >> 1;
    const int rrow = lane & 15, g = lane >> 4;
    const int o = ot * 16 + rrow;

    // -- weight staging: 48 rows x 108 float4 granules, lane-contiguous
    const float* wbase = wgt + (size_t)l * NK;
    float4 va[7], vb[6];
#pragma unroll
    for (int i = 0; i < 7; ++i) {
        const int gi = t + i * 384;
        const int row = gi / 108, c = gi - row * 108;
        va[i] = *(const float4*)(wbase + (size_t)row * (NL * NK) + c * 4);
    }
#pragma unroll
    for (int i = 0; i < 6; ++i) {
        const int gi = t + (7 + i) * 384;
        const int row = gi / 108, c = gi - row * 108;
        vb[i] = *(const float4*)(wbase + (size_t)row * (NL * NK) + c * 4);
    }
    float4 vt;
    if (t < 5184 - 13 * 384) {
        const int gi = t + 13 * 384;
        const int row = gi / 108, c = gi - row * 108;
        vt = *(const float4*)(wbase + (size_t)row * (NL * NK) + c * 4);
    }

    // -- A-fragments: dense reads from unf (issued early, independent of LDS)
    const __bf16* pa = unf + (size_t)l * UROW + (mt * 16 + rrow) * KPAD + g * 8;
    bf16x8 av[14];
#pragma unroll
    for (int ks = 0; ks < 14; ++ks) av[ks] = *(const bf16x8*)(pa + ks * 32);

    const float bsv = bias[o];

    // -- zero ws K-pad [432,456): 48 rows x 3 bf16x8
    if (t < 144) {
        const int r = t / 3, ch = t - r * 3;
        bf16x8 z = {};
        *(bf16x8*)&ws[r * PITCH + NK + ch * 8] = z;
    }

    // -- drain & convert weights f32 -> bf16 LDS
#pragma unroll
    for (int i = 0; i < 7; ++i) {
        const int gi = t + i * 384;
        const int row = gi / 108, c = gi - row * 108;
        bf16x4 bv4; bv4[0] = (__bf16)va[i].x; bv4[1] = (__bf16)va[i].y;
        bv4[2] = (__bf16)va[i].z; bv4[3] = (__bf16)va[i].w;
        *(bf16x4*)&ws[row * PITCH + c * 4] = bv4;
    }
#pragma unroll
    for (int i = 0; i < 6; ++i) {
        const int gi = t + (7 + i) * 384;
        const int row = gi / 108, c = gi - row * 108;
        bf16x4 bv4; bv4[0] = (__bf16)vb[i].x; bv4[1] = (__bf16)vb[i].y;
        bv4[2] = (__bf16)vb[i].z; bv4[3] = (__bf16)vb[i].w;
        *(bf16x4*)&ws[row * PITCH + c * 4] = bv4;
    }
    if (t < 5184 - 13 * 384) {
        const int gi = t + 13 * 384;
        const int row = gi / 108, c = gi - row * 108;
        bf16x4 bv4; bv4[0] = (__bf16)vt.x; bv4[1] = (__bf16)vt.y;
        bv4[2] = (__bf16)vt.z; bv4[3] = (__bf16)vt.w;
        *(bf16x4*)&ws[row * PITCH + c * 4] = bv4;
    }

    __syncthreads();

    // -- 14 MFMA, B from LDS, A from regs
    const __bf16* pb = &ws[o * PITCH + g * 8];
    f32x4 acc = {0.f, 0.f, 0.f, 0.f};
#pragma unroll
    for (int ks = 0; ks < 14; ++ks) {
        bf16x8 bv = *(const bf16x8*)(pb + ks * 32);
        acc = __builtin_amdgcn_mfma_f32_16x16x32_bf16(av[ks], bv, acc, 0, 0, 0);
    }

    // -- epilogue: out_t[l][b*48+o], contiguous per block
#pragma unroll
    for (int r = 0; r < 4; ++r) {
        const int b = mt * 16 + g * 4 + r;
        out_t[(size_t)l * NM + b * NO + o] = acc[r] + bsv;
    }
}

// ---------------- K3: transpose  out[m][l] = out_t[l][m] ----------------
__global__ __launch_bounds__(256)
void lc2d_transpose(const float* __restrict__ src, float* __restrict__ dst) {
    __shared__ float tile[32][33];
    const int bid = blockIdx.x;
    const int mt = bid % (NM / 32), lt = bid / (NM / 32);
    const int m0 = mt * 32, l0 = lt * 32;
    const int tid = threadIdx.x;
    const int c = tid & 31, rq = tid >> 5;
#pragma unroll
    for (int p = 0; p < 4; ++p) {
        const int lr = p * 8 + rq;
        tile[lr][c] = src[(size_t)(l0 + lr) * NM + m0 + c];
    }
    __syncthreads();
#pragma unroll
    for (int p = 0; p < 4; ++p) {
        const int mr = p * 8 + rq;
        dst[(size_t)(m0 + mr) * NL + l0 + c] = tile[c][mr];
    }
}

// ---------------- fallback (R4): fused staging kernel ----------------
template <int MODE>   // 0 = direct scattered stores, 1 = transposed scratch
__global__ __launch_bounds__(384, 3)
void lc2d_fallback(const float* __restrict__ x, const float* __restrict__ wgt,
                   const float* __restrict__ bias, float* __restrict__ outp) {
    __shared__ __bf16 xs[NB * PITCH];
    __shared__ __bf16 ws[NO * PITCH];
    const int t = threadIdx.x;
    const int bid = blockIdx.x;
    const int l = (bid & 7) * 512 + (bid >> 3);
    const int h = l >> 6;
    const int w = l & 63;
    const float* wbase = wgt + (size_t)l * NK;
    float4 va[7], vb[6];
#pragma unroll
    for (int i = 0; i < 7; ++i) {
        const int gi = t + i * 384;
        const int row = gi / 108, c = gi - row * 108;
        va[i] = *(const float4*)(wbase + (size_t)row * (NL * NK) + c * 4);
    }
#pragma unroll
    for (int i = 0; i < 6; ++i) {
        const int gi = t + (7 + i) * 384;
        const int row = gi / 108, c = gi - row * 108;
        vb[i] = *(const float4*)(wbase + (size_t)row * (NL * NK) + c * 4);
    }
    float4 vt;
    if (t < 5184 - 13 * 384) {
        const int gi = t + 13 * 384;
        const int row = gi / 108, c = gi - row * 108;
        vt = *(const float4*)(wbase + (size_t)row * (NL * NK) + c * 4);
    }
    float xv[4][9];
#pragma unroll
    for (int it = 0; it < 4; ++it) {
        const int idx = t + it * 384;
        const int b = idx / NC, c = idx - b * NC;
        const float* xb = x + ((size_t)(b * NC + c)) * (NH * NW);
#pragma unroll
        for (int di = 0; di < 3; ++di) {
            const int y = h + di - 1;
            const bool yok = (unsigned)y < (unsigned)NH;
#pragma unroll
            for (int dj = 0; dj < 3; ++dj) {
                const int xc = w + dj - 1;
                xv[it][di * 3 + dj] =
                    (yok && (unsigned)xc < (unsigned)NW) ? xb[y * NW + xc] : 0.0f;
            }
        }
    }
    {
        bf16x8 z = {};
        if (t < 144) { const int r = t / 3, ch = t - r * 3; *(bf16x8*)&ws[r * PITCH + NK + ch * 8] = z; }
        else if (t < 240) { const int q = t - 144; const int r = q / 3, ch = q - r * 3; *(bf16x8*)&xs[r * PITCH + NK + ch * 8] = z; }
    }
#pragma unroll
    for (int i = 0; i < 7; ++i) {
        const int gi = t + i * 384;
        const int row = gi / 108, c = gi - row * 108;
        bf16x4 bv4; bv4[0] = (__bf16)va[i].x; bv4[1] = (__bf16)va[i].y;
        bv4[2] = (__bf16)va[i].z; bv4[3] = (__bf16)va[i].w;
        *(bf16x4*)&ws[row * PITCH + c * 4] = bv4;
    }
#pragma unroll
    for (int i = 0; i < 6; ++i) {
        const int gi = t + (7 + i) * 384;
        const int row = gi / 108, c = gi - row * 108;
        bf16x4 bv4; bv4[0] = (__bf16)vb[i].x; bv4[1] = (__bf16)vb[i].y;
        bv4[2] = (__bf16)vb[i].z; bv4[3] = (__bf16)vb[i].w;
        *(bf16x4*)&ws[row * PITCH + c * 4] = bv4;
    }
    if (t < 5184 - 13 * 384) {
        const int gi = t + 13 * 384;
        const int row = gi / 108, c = gi - row * 108;
        bf16x4 bv4; bv4[0] = (__bf16)vt.x; bv4[1] = (__bf16)vt.y;
        bv4[2] = (__bf16)vt.z; bv4[3] = (__bf16)vt.w;
        *(bf16x4*)&ws[row * PITCH + c * 4] = bv4;
    }
#pragma unroll
    for (int it = 0; it < 4; ++it) {
        const int idx = t + it * 384;
        const int b = idx / NC, c = idx - b * NC;
        __bf16* dst = &xs[b * PITCH + c * 9];
#pragma unroll
        for (int k9 = 0; k9 < 9; ++k9) dst[k9] = (__bf16)xv[it][k9];
    }
    __syncthreads();
    const int lane = t & 63, wid = t >> 6;
    const int mt = wid & 1, ot = wid >> 1;
    const int rrow = lane & 15, g = lane >> 4;
    const int o = ot * 16 + rrow;
    const __bf16* pa = &xs[(mt * 16 + rrow) * PITCH + g * 8];
    const __bf16* pb = &ws[o * PITCH + g * 8];
    f32x4 acc = {0.f, 0.f, 0.f, 0.f};
#pragma unroll
    for (int ks = 0; ks < 14; ++ks) {
        bf16x8 avv = *(const bf16x8*)(pa + ks * 32);
        bf16x8 bvv = *(const bf16x8*)(pb + ks * 32);
        acc = __builtin_amdgcn_mfma_f32_16x16x32_bf16(avv, bvv, acc, 0, 0, 0);
    }
    const float bsv = bias[o];
#pragma unroll
    for (int r = 0; r < 4; ++r) {
        const int b = mt * 16 + g * 4 + r;
        if (MODE == 1) outp[(size_t)l * NM + b * NO + o] = acc[r] + bsv;
        else           outp[((size_t)(b * NO + o)) * NL + l] = acc[r] + bsv;
    }
}

extern "C" void kernel_launch(void* const* d_in, const int* in_sizes, int n_in,
                              void* d_out, int out_size, void* d_ws, size_t ws_size,
                              hipStream_t stream) {
    const float* x    = (const float*)d_in[0];
    const float* wgt  = (const float*)d_in[1];
    const float* bias = (const float*)d_in[2];
    float* out = (float*)d_out;

    const size_t unf_bytes  = (size_t)NL * NB * KPAD * sizeof(__bf16);  // 117.4 MB
    const size_t outt_bytes = (size_t)NL * NM * sizeof(float);          // 25.2 MB

    if (ws_size >= unf_bytes + outt_bytes) {
        __bf16* unf = (__bf16*)d_ws;
        float* out_t = (float*)((char*)d_ws + unf_bytes);
        lc2d_unfold<<<dim3(NH * NB), dim3(256), 0, stream>>>(x, unf);
        lc2d_main<<<dim3(NL), dim3(384), 0, stream>>>(unf, wgt, bias, out_t);
        lc2d_transpose<<<dim3((NM / 32) * (NL / 32)), dim3(256), 0, stream>>>(out_t, out);
    } else if (ws_size >= outt_bytes) {
        float* out_t = (float*)d_ws;
        lc2d_fallback<1><<<dim3(NL), dim3(384), 0, stream>>>(x, wgt, bias, out_t);
        lc2d_transpose<<<dim3((NM / 32) * (NL / 32)), dim3(256), 0, stream>>>(out_t, out);
    } else {
        lc2d_fallback<0><<<dim3(NL), dim3(384), 0, stream>>>(x, wgt, bias, out);
    }
}

// Round 6
// 179.627 us; speedup vs baseline: 1.6638x; 1.0217x over previous
//
#include <hip/hip_runtime.h>
#include <hip/hip_bf16.h>

// LocallyConnected2d: x(32,48,64,64) f32, weight(48,64,64,48,3,3) f32, bias(48) f32
// out(32,48,64,64) f32.  Per-location GEMM M=32(b) x N=48(o) x K=432, bf16 MFMA.
//
// R6: main kernel rebuilt around global_load_lds (zero-VGPR weight staging,
// compiler can't serialize it). Weights staged as f32 rows (452-dword pitch)
// into 28.9 KB LDS -> 5 blocks/CU; bf16 conversion on fragment read.
// Block = (l, o-16); A-frags from unf (bf16, L2/L3) to regs. unfold/transpose
// unchanged from R5.

#define NB 32
#define NC 48
#define NO 48
#define NH 64
#define NW 64
#define NL 4096
#define NK 432
#define KPAD 448     // padded K (14*32)
#define NM 1536      // NB*NO
#define UROW 14336   // NB*KPAD  (elems per l in unf)
#define WROW 452     // dwords per LDS weight row (452%32=4 -> staggered banks)
#define WGRAN 113    // 16-B granules per LDS weight row
#define PITCH 456    // fallback kernels' LDS pitch (bf16)

typedef __bf16 bf16x8 __attribute__((ext_vector_type(8)));
typedef __bf16 bf16x4 __attribute__((ext_vector_type(4)));
typedef float f32x4 __attribute__((ext_vector_type(4)));

// ---------------- K1: unfold  x -> unf[l][b][kp448]  (bf16) ----------------
__global__ __launch_bounds__(256)
void lc2d_unfold(const float* __restrict__ x, __bf16* __restrict__ unf) {
    __shared__ float xl[NC * 3 * 66];   // row-padded [c*3+yy][66], col 0/65 = halo
    const int bid = blockIdx.x;
    const int h = bid >> 5;             // 0..63
    const int b = bid & 31;             // 0..31
    const int t = threadIdx.x;

#pragma unroll
    for (int it = 0; it < 36; ++it) {
        const int idx = t + it * 256;
        const int row = idx >> 6;       // c*3+yy, 0..143
        const int w = idx & 63;
        const int c = row / 3, yy = row - c * 3;
        const int y = h + yy - 1;
        float v = 0.0f;
        if ((unsigned)y < (unsigned)NH)
            v = x[(((size_t)(b * NC + c)) * NH + y) * NW + w];
        xl[row * 66 + 1 + w] = v;
    }
    if (t < 144) { xl[t * 66] = 0.0f; xl[t * 66 + 65] = 0.0f; }
    __syncthreads();

    __bf16* dst = unf + ((size_t)h * 64 * NB + b) * KPAD;
#pragma unroll
    for (int it = 0; it < 14; ++it) {
        const int idx = t + it * 256;   // 0..3583
        const int w = idx / 56, kc = idx - w * 56;
        bf16x8 val = {};
        if (kc < 54) {                  // kc 54,55 are K-pad -> zeros
#pragma unroll
            for (int j = 0; j < 8; ++j) {
                const int kp = kc * 8 + j;
                const int c = kp / 9, r9 = kp - c * 9;
                const int di = r9 / 3, dj = r9 - di * 3;
                val[j] = (__bf16)xl[(c * 3 + di) * 66 + w + dj];
            }
        }
        *(bf16x8*)(dst + (size_t)w * UROW + kc * 8) = val;
    }
}

// ---------------- K2: main v2  (l, o-16) blocks, global_load_lds weights ----------------
__global__ __launch_bounds__(128)
void lc2d_main2(const __bf16* __restrict__ unf, const float* __restrict__ wgt,
                const float* __restrict__ bias, float* __restrict__ out_t) {
    __shared__ float wsf[16 * WROW];    // 28928 B -> 5 blocks/CU

    const int t = threadIdx.x;
    const int bid = blockIdx.x;
    // XCD-chunked: consecutive u on one XCD; 3 consecutive u = same l (unf L2 reuse)
    const int u = (bid & 7) * 1536 + (bid >> 3);   // grid 12288 = 8*1536
    const int l = u / 3;
    const int ot = u - l * 3;

    const int lane = t & 63, mt = t >> 6;          // wave mt: b-half
    const int rrow = lane & 15, g = lane >> 4;
    const int o = ot * 16 + rrow;

    // -- A-fragments: dense bf16 reads from unf (issued first, to regs)
    const __bf16* pa = unf + (size_t)l * UROW + (mt * 16 + rrow) * KPAD + g * 8;
    bf16x8 av[14];
#pragma unroll
    for (int ks = 0; ks < 14; ++ks) av[ks] = *(const bf16x8*)(pa + ks * 32);

    const float bsv = bias[o];

    // -- weight staging: 1808 granules (16 rows x 113) via global_load_lds,
    //    zero VGPR cost, full stream in flight.  slot s -> row s/113, gran s%113.
#pragma unroll
    for (int i = 0; i < 14; ++i) {
        const int s = i * 128 + t;
        const int row = s / WGRAN, r = s - row * WGRAN;
        const int gg = (r < 108) ? r : 0;   // pad granules: load row start (zeroed later)
        const float* src = wgt + ((size_t)(ot * 16 + row) * NL + l) * NK + gg * 4;
        __builtin_amdgcn_global_load_lds((const void*)src, (void*)&wsf[(size_t)s * 4], 16, 0, 0);
    }
    if (t < 16) {                           // remainder: slots 1792..1807
        const int s = 14 * 128 + t;
        const int row = s / WGRAN, r = s - row * WGRAN;
        const int gg = (r < 108) ? r : 0;
        const float* src = wgt + ((size_t)(ot * 16 + row) * NL + l) * NK + gg * 4;
        __builtin_amdgcn_global_load_lds((const void*)src, (void*)&wsf[(size_t)s * 4], 16, 0, 0);
    }

    __syncthreads();    // drains vmcnt: weights in LDS, av[] in regs

    // -- zero K-pad granules 108..111 of each row (dwords 432..447)
    if (t < 64) {
        const int row = t >> 2, q = t & 3;
        f32x4 z = {0.f, 0.f, 0.f, 0.f};
        *(f32x4*)&wsf[(size_t)(row * WGRAN + 108 + q) * 4] = z;
    }
    __syncthreads();

    // -- 14 MFMA; B-frags read f32 from LDS, cvt to bf16 in-reg
    const float* pb = &wsf[rrow * WROW + g * 8];
    f32x4 acc = {0.f, 0.f, 0.f, 0.f};
#pragma unroll
    for (int ks = 0; ks < 14; ++ks) {
        f32x4 b0 = *(const f32x4*)(pb + ks * 32);
        f32x4 b1 = *(const f32x4*)(pb + ks * 32 + 4);
        bf16x8 bv;
        bv[0] = (__bf16)b0.x; bv[1] = (__bf16)b0.y; bv[2] = (__bf16)b0.z; bv[3] = (__bf16)b0.w;
        bv[4] = (__bf16)b1.x; bv[5] = (__bf16)b1.y; bv[6] = (__bf16)b1.z; bv[7] = (__bf16)b1.w;
        acc = __builtin_amdgcn_mfma_f32_16x16x32_bf16(av[ks], bv, acc, 0, 0, 0);
    }

    // -- epilogue: C layout col(lane&15)=o, row((lane>>4)*4+r)=b -> out_t[l][b*48+o]
#pragma unroll
    for (int r = 0; r < 4; ++r) {
        const int b = mt * 16 + g * 4 + r;
        out_t[(size_t)l * NM + b * NO + o] = acc[r] + bsv;
    }
}

// ---------------- K3: transpose  out[m][l] = out_t[l][m] ----------------
__global__ __launch_bounds__(256)
void lc2d_transpose(const float* __restrict__ src, float* __restrict__ dst) {
    __shared__ float tile[32][33];
    const int bid = blockIdx.x;
    const int mt = bid % (NM / 32), lt = bid / (NM / 32);
    const int m0 = mt * 32, l0 = lt * 32;
    const int tid = threadIdx.x;
    const int c = tid & 31, rq = tid >> 5;
#pragma unroll
    for (int p = 0; p < 4; ++p) {
        const int lr = p * 8 + rq;
        tile[lr][c] = src[(size_t)(l0 + lr) * NM + m0 + c];
    }
    __syncthreads();
#pragma unroll
    for (int p = 0; p < 4; ++p) {
        const int mr = p * 8 + rq;
        dst[(size_t)(m0 + mr) * NL + l0 + c] = tile[c][mr];
    }
}

// ---------------- fallback (R4): fused staging kernel ----------------
template <int MODE>   // 0 = direct scattered stores, 1 = transposed scratch
__global__ __launch_bounds__(384, 3)
void lc2d_fallback(const float* __restrict__ x, const float* __restrict__ wgt,
                   const float* __restrict__ bias, float* __restrict__ outp) {
    __shared__ __bf16 xs[NB * PITCH];
    __shared__ __bf16 ws[NO * PITCH];
    const int t = threadIdx.x;
    const int bid = blockIdx.x;
    const int l = (bid & 7) * 512 + (bid >> 3);
    const int h = l >> 6;
    const int w = l & 63;
    const float* wbase = wgt + (size_t)l * NK;
    float4 va[7], vb[6];
#pragma unroll
    for (int i = 0; i < 7; ++i) {
        const int gi = t + i * 384;
        const int row = gi / 108, c = gi - row * 108;
        va[i] = *(const float4*)(wbase + (size_t)row * (NL * NK) + c * 4);
    }
#pragma unroll
    for (int i = 0; i < 6; ++i) {
        const int gi = t + (7 + i) * 384;
        const int row = gi / 108, c = gi - row * 108;
        vb[i] = *(const float4*)(wbase + (size_t)row * (NL * NK) + c * 4);
    }
    float4 vt;
    if (t < 5184 - 13 * 384) {
        const int gi = t + 13 * 384;
        const int row = gi / 108, c = gi - row * 108;
        vt = *(const float4*)(wbase + (size_t)row * (NL * NK) + c * 4);
    }
    float xv[4][9];
#pragma unroll
    for (int it = 0; it < 4; ++it) {
        const int idx = t + it * 384;
        const int b = idx / NC, c = idx - b * NC;
        const float* xb = x + ((size_t)(b * NC + c)) * (NH * NW);
#pragma unroll
        for (int di = 0; di < 3; ++di) {
            const int y = h + di - 1;
            const bool yok = (unsigned)y < (unsigned)NH;
#pragma unroll
            for (int dj = 0; dj < 3; ++dj) {
                const int xc = w + dj - 1;
                xv[it][di * 3 + dj] =
                    (yok && (unsigned)xc < (unsigned)NW) ? xb[y * NW + xc] : 0.0f;
            }
        }
    }
    {
        bf16x8 z = {};
        if (t < 144) { const int r = t / 3, ch = t - r * 3; *(bf16x8*)&ws[r * PITCH + NK + ch * 8] = z; }
        else if (t < 240) { const int q = t - 144; const int r = q / 3, ch = q - r * 3; *(bf16x8*)&xs[r * PITCH + NK + ch * 8] = z; }
    }
#pragma unroll
    for (int i = 0; i < 7; ++i) {
        const int gi = t + i * 384;
        const int row = gi / 108, c = gi - row * 108;
        bf16x4 bv4; bv4[0] = (__bf16)va[i].x; bv4[1] = (__bf16)va[i].y;
        bv4[2] = (__bf16)va[i].z; bv4[3] = (__bf16)va[i].w;
        *(bf16x4*)&ws[row * PITCH + c * 4] = bv4;
    }
#pragma unroll
    for (int i = 0; i < 6; ++i) {
        const int gi = t + (7 + i) * 384;
        const int row = gi / 108, c = gi - row * 108;
        bf16x4 bv4; bv4[0] = (__bf16)vb[i].x; bv4[1] = (__bf16)vb[i].y;
        bv4[2] = (__bf16)vb[i].z; bv4[3] = (__bf16)vb[i].w;
        *(bf16x4*)&ws[row * PITCH + c * 4] = bv4;
    }
    if (t < 5184 - 13 * 384) {
        const int gi = t + 13 * 384;
        const int row = gi / 108, c = gi - row * 108;
        bf16x4 bv4; bv4[0] = (__bf16)vt.x; bv4[1] = (__bf16)vt.y;
        bv4[2] = (__bf16)vt.z; bv4[3] = (__bf16)vt.w;
        *(bf16x4*)&ws[row * PITCH + c * 4] = bv4;
    }
#pragma unroll
    for (int it = 0; it < 4; ++it) {
        const int idx = t + it * 384;
        const int b = idx / NC, c = idx - b * NC;
        __bf16* dst = &xs[b * PITCH + c * 9];
#pragma unroll
        for (int k9 = 0; k9 < 9; ++k9) dst[k9] = (__bf16)xv[it][k9];
    }
    __syncthreads();
    const int lane = t & 63, wid = t >> 6;
    const int mt = wid & 1, ot = wid >> 1;
    const int rrow = lane & 15, g = lane >> 4;
    const int o = ot * 16 + rrow;
    const __bf16* pa = &xs[(mt * 16 + rrow) * PITCH + g * 8];
    const __bf16* pb = &ws[o * PITCH + g * 8];
    f32x4 acc = {0.f, 0.f, 0.f, 0.f};
#pragma unroll
    for (int ks = 0; ks < 14; ++ks) {
        bf16x8 avv = *(const bf16x8*)(pa + ks * 32);
        bf16x8 bvv = *(const bf16x8*)(pb + ks * 32);
        acc = __builtin_amdgcn_mfma_f32_16x16x32_bf16(avv, bvv, acc, 0, 0, 0);
    }
    const float bsv = bias[o];
#pragma unroll
    for (int r = 0; r < 4; ++r) {
        const int b = mt * 16 + g * 4 + r;
        if (MODE == 1) outp[(size_t)l * NM + b * NO + o] = acc[r] + bsv;
        else           outp[((size_t)(b * NO + o)) * NL + l] = acc[r] + bsv;
    }
}

extern "C" void kernel_launch(void* const* d_in, const int* in_sizes, int n_in,
                              void* d_out, int out_size, void* d_ws, size_t ws_size,
                              hipStream_t stream) {
    const float* x    = (const float*)d_in[0];
    const float* wgt  = (const float*)d_in[1];
    const float* bias = (const float*)d_in[2];
    float* out = (float*)d_out;

    const size_t unf_bytes  = (size_t)NL * NB * KPAD * sizeof(__bf16);  // 117.4 MB
    const size_t outt_bytes = (size_t)NL * NM * sizeof(float);          // 25.2 MB

    if (ws_size >= unf_bytes + outt_bytes) {
        __bf16* unf = (__bf16*)d_ws;
        float* out_t = (float*)((char*)d_ws + unf_bytes);
        lc2d_unfold<<<dim3(NH * NB), dim3(256), 0, stream>>>(x, unf);
        lc2d_main2<<<dim3(NL * 3), dim3(128), 0, stream>>>(unf, wgt, bias, out_t);
        lc2d_transpose<<<dim3((NM / 32) * (NL / 32)), dim3(256), 0, stream>>>(out_t, out);
    } else if (ws_size >= outt_bytes) {
        float* out_t = (float*)d_ws;
        lc2d_fallback<1><<<dim3(NL), dim3(384), 0, stream>>>(x, wgt, bias, out_t);
        lc2d_transpose<<<dim3((NM / 32) * (NL / 32)), dim3(256), 0, stream>>>(out_t, out);
    } else {
        lc2d_fallback<0><<<dim3(NL), dim3(384), 0, stream>>>(x, wgt, bias, out);
    }
}